// Round 2
// baseline (170.789 us; speedup 1.0000x reference)
//
#include <hip/hip_runtime.h>
#include <float.h>

// Closing = erosion(identity) ∘ dilation(sum over CIN), K=5, edge padding.
// v2: per-block output tile 32x64, 256 threads.
//  - x staged one channel at a time (LDS 12.2KB), dilation max accumulated in
//    registers across the 3 channel passes -> total LDS 21.9KB -> 7 blocks/CU.
//  - 8-wide strips everywhere: 12-float windows = 3x ds_read_b128 per row.
//  - strides: sx 76 (granule step 3 mod 8), sdil 68 (step 1 mod 8) -> spread banks.
//  - edge-pad semantics of the erosion input fused into the dilation writeback
//    (row-2/col-2 owners replicate into phantom slots) -> erosion is branch-free.

namespace {
constexpr int HH = 256, WW = 256;
constexpr int CI = 3;
constexpr int TW = 64, TH = 32;   // output tile
constexpr int DW = 68, DH = 36;   // dilated tile, stride 68
constexpr int XW = 76, XH = 40;   // x tile (one channel), stride 76
}

__global__ __launch_bounds__(256, 6)
void closing_v2(const float* __restrict__ x, const float* __restrict__ wd,
                const float* __restrict__ we, float* __restrict__ out) {
    __shared__ __align__(16) float sx[XH * XW];     // 12160 B
    __shared__ __align__(16) float sdil[DH * DW];   //  9792 B

    const int tid = threadIdx.x;
    const int bx = blockIdx.x, by = blockIdx.y, z = blockIdx.z;
    const int o = z & 15, b = z >> 4;
    const int i0 = by * TH, j0 = bx * TW;
    const float* xb = x + (size_t)b * (CI * HH * WW);

    // dilation task assignment: 36 rows x 9 strips (8-wide) = 324 tasks
    const int r0 = tid / 9, s0 = tid - r0 * 9;
    const int t2 = tid + 256;
    const int r1 = t2 / 9, s1 = t2 - r1 * 9;
    const bool has2 = (t2 < DH * 9);   // tid < 68

    float acc0[8], acc1[8];
#pragma unroll
    for (int j = 0; j < 8; ++j) { acc0[j] = 0.f; acc1[j] = 0.f; }

    for (int c = 0; c < CI; ++c) {
        // ---- stage channel c: 3040 dwords, linear LDS writes (conflict-free) ----
        {
            const float* xc = xb + c * (HH * WW);
            int rs = tid / XW, cs = tid - rs * XW;
#pragma unroll
            for (int k = 0; k < 12; ++k) {
                const int idx = tid + k * 256;
                if (idx < XH * XW) {
                    int gi = i0 - 4 + rs; gi = min(max(gi, 0), HH - 1);
                    int gj = j0 - 4 + cs; gj = min(max(gj, 0), WW - 1);
                    sx[idx] = xc[(gi << 8) + gj];
                }
                cs += 256 - 3 * XW;   // +28
                rs += 3;
                if (cs >= XW) { cs -= XW; rs += 1; }
            }
        }
        __syncthreads();

        const float* wr = wd + (o * CI + c) * 25;   // uniform -> SGPRs

        // ---- dilation task(s): per-channel 5x5 max over 8-wide strip ----
        {
            float m[8];
#pragma unroll
            for (int j = 0; j < 8; ++j) m[j] = -FLT_MAX;
#pragma unroll
            for (int dd = 0; dd < 5; ++dd) {
                const float* p = &sx[(r0 + dd) * XW + 8 * s0];
                const float4 a  = *(const float4*)p;
                const float4 bq = *(const float4*)(p + 4);
                const float4 cq = *(const float4*)(p + 8);
                const float win[12] = {a.x,a.y,a.z,a.w, bq.x,bq.y,bq.z,bq.w,
                                       cq.x,cq.y,cq.z,cq.w};
                const float w0 = wr[dd*5+0], w1 = wr[dd*5+1], w2 = wr[dd*5+2],
                            w3 = wr[dd*5+3], w4 = wr[dd*5+4];
#pragma unroll
                for (int j = 0; j < 8; ++j) {
                    m[j] = fmaxf(fmaxf(m[j], win[j]   + w0), win[j+1] + w1);
                    m[j] = fmaxf(fmaxf(m[j], win[j+2] + w2), win[j+3] + w3);
                    m[j] = fmaxf(m[j], win[j+4] + w4);
                }
            }
#pragma unroll
            for (int j = 0; j < 8; ++j) acc0[j] += m[j];
        }
        if (has2) {
            float m[8];
#pragma unroll
            for (int j = 0; j < 8; ++j) m[j] = -FLT_MAX;
#pragma unroll
            for (int dd = 0; dd < 5; ++dd) {
                const float* p = &sx[(r1 + dd) * XW + 8 * s1];
                const float4 a  = *(const float4*)p;
                const float4 bq = *(const float4*)(p + 4);
                const float4 cq = *(const float4*)(p + 8);
                const float win[12] = {a.x,a.y,a.z,a.w, bq.x,bq.y,bq.z,bq.w,
                                       cq.x,cq.y,cq.z,cq.w};
                const float w0 = wr[dd*5+0], w1 = wr[dd*5+1], w2 = wr[dd*5+2],
                            w3 = wr[dd*5+3], w4 = wr[dd*5+4];
#pragma unroll
                for (int j = 0; j < 8; ++j) {
                    m[j] = fmaxf(fmaxf(m[j], win[j]   + w0), win[j+1] + w1);
                    m[j] = fmaxf(fmaxf(m[j], win[j+2] + w2), win[j+3] + w3);
                    m[j] = fmaxf(m[j], win[j+4] + w4);
                }
            }
#pragma unroll
            for (int j = 0; j < 8; ++j) acc1[j] += m[j];
        }
        if (c < CI - 1) __syncthreads();   // protect sx before restage
    }

    // ---- write sdil, edge-pad replication fused in ----
    {
        // task 0
        {
            int r = r0, s = s0;
            if (bx == 0 && s == 0) { acc0[0] = acc0[1] = acc0[2]; }
            if (bx == 3 && s == 8) { acc0[2] = acc0[3] = acc0[1]; }
            const bool shadow = (by == 0 && r < 2) || (by == 7 && r > 33);
            if (!shadow) {
                const float4 q0 = make_float4(acc0[0], acc0[1], acc0[2], acc0[3]);
                const float4 q1 = make_float4(acc0[4], acc0[5], acc0[6], acc0[7]);
                float* bp = &sdil[r * DW + 8 * s];
                *(float4*)bp = q0; if (s < 8) *(float4*)(bp + 4) = q1;
                if (by == 0 && r == 2) {
                    *(float4*)&sdil[0*DW + 8*s] = q0; if (s<8) *(float4*)&sdil[0*DW + 8*s + 4] = q1;
                    *(float4*)&sdil[1*DW + 8*s] = q0; if (s<8) *(float4*)&sdil[1*DW + 8*s + 4] = q1;
                }
                if (by == 7 && r == 33) {
                    *(float4*)&sdil[34*DW + 8*s] = q0; if (s<8) *(float4*)&sdil[34*DW + 8*s + 4] = q1;
                    *(float4*)&sdil[35*DW + 8*s] = q0; if (s<8) *(float4*)&sdil[35*DW + 8*s + 4] = q1;
                }
            }
        }
        if (has2) {
            int r = r1, s = s1;
            if (bx == 0 && s == 0) { acc1[0] = acc1[1] = acc1[2]; }
            if (bx == 3 && s == 8) { acc1[2] = acc1[3] = acc1[1]; }
            const bool shadow = (by == 0 && r < 2) || (by == 7 && r > 33);
            if (!shadow) {
                const float4 q0 = make_float4(acc1[0], acc1[1], acc1[2], acc1[3]);
                const float4 q1 = make_float4(acc1[4], acc1[5], acc1[6], acc1[7]);
                float* bp = &sdil[r * DW + 8 * s];
                *(float4*)bp = q0; if (s < 8) *(float4*)(bp + 4) = q1;
                if (by == 0 && r == 2) {
                    *(float4*)&sdil[0*DW + 8*s] = q0; if (s<8) *(float4*)&sdil[0*DW + 8*s + 4] = q1;
                    *(float4*)&sdil[1*DW + 8*s] = q0; if (s<8) *(float4*)&sdil[1*DW + 8*s + 4] = q1;
                }
                if (by == 7 && r == 33) {
                    *(float4*)&sdil[34*DW + 8*s] = q0; if (s<8) *(float4*)&sdil[34*DW + 8*s + 4] = q1;
                    *(float4*)&sdil[35*DW + 8*s] = q0; if (s<8) *(float4*)&sdil[35*DW + 8*s + 4] = q1;
                }
            }
        }
    }
    __syncthreads();

    // ---- erosion: branch-free, 8-wide strip per thread (32 rows x 8 strips) ----
    {
        const int er = tid >> 3, es = tid & 7;
        const float* ew = we + o * 25;   // uniform -> SGPRs
        float rm[8];
#pragma unroll
        for (int j = 0; j < 8; ++j) rm[j] = FLT_MAX;
#pragma unroll
        for (int dd = 0; dd < 5; ++dd) {
            const float* p = &sdil[(er + dd) * DW + 8 * es];
            const float4 a  = *(const float4*)p;
            const float4 bq = *(const float4*)(p + 4);
            const float4 cq = *(const float4*)(p + 8);
            const float win[12] = {a.x,a.y,a.z,a.w, bq.x,bq.y,bq.z,bq.w,
                                   cq.x,cq.y,cq.z,cq.w};
            const float e0 = ew[dd*5+0], e1 = ew[dd*5+1], e2 = ew[dd*5+2],
                        e3 = ew[dd*5+3], e4 = ew[dd*5+4];
#pragma unroll
            for (int j = 0; j < 8; ++j) {
                rm[j] = fminf(fminf(rm[j], win[j]   - e0), win[j+1] - e1);
                rm[j] = fminf(fminf(rm[j], win[j+2] - e2), win[j+3] - e3);
                rm[j] = fminf(rm[j], win[j+4] - e4);
            }
        }
        float* op = &out[((size_t)z << 16) + ((size_t)(i0 + er) << 8) + j0 + 8 * es];
        *(float4*)op       = make_float4(rm[0], rm[1], rm[2], rm[3]);
        *(float4*)(op + 4) = make_float4(rm[4], rm[5], rm[6], rm[7]);
    }
}

extern "C" void kernel_launch(void* const* d_in, const int* in_sizes, int n_in,
                              void* d_out, int out_size, void* d_ws, size_t ws_size,
                              hipStream_t stream) {
    const float* x  = (const float*)d_in[0];   // (4,3,256,256)
    const float* wd = (const float*)d_in[1];   // (16,3,5,5)
    const float* we = (const float*)d_in[2];   // (16,5,5)
    float* out = (float*)d_out;                // (4,16,256,256)

    dim3 grid(WW / TW, HH / TH, 4 * 16);       // (4, 8, 64)
    closing_v2<<<grid, dim3(256), 0, stream>>>(x, wd, we, out);
}

// Round 3
// 110.119 us; speedup vs baseline: 1.5510x; 1.5510x over previous
//
#include <hip/hip_runtime.h>
#include <float.h>

// Closing = erosion(identity) ∘ dilation(sum over CIN=3), K=5, edge padding.
// v3: 32x32 output tile, 256 threads. All 3 x-channels staged once (no
// accumulator-across-barrier -> no scratch spill, unlike v2).
//  - dilation: 81 tasks of 4rows x 4cols (1.0 LDS b128 per out per channel)
//  - erosion: 128 tasks of 1row x 8cols, branch-free via pad replication
//  - strides 44 floats (11 quads, odd) + lane maps spread bank groups
//  - all hot-path state in named float4s (SROA-proof, no local arrays)

namespace {
constexpr int HH = 256, WW = 256, CI = 3;
constexpr int TT = 32;            // output tile
constexpr int DS = 44;            // sdil row stride (floats), 11 quads
constexpr int XS = 44;            // sx row stride
constexpr int XR = 40;            // sx rows / valid cols
constexpr int XCH = XR * XS;      // 1760 floats per channel
}

__device__ __forceinline__ float4 dapp(float4 m, float4 A, float4 B,
                                       float w0, float w1, float w2, float w3, float w4) {
    m.x = fmaxf(fmaxf(fmaxf(m.x, A.x + w0), fmaxf(A.y + w1, A.z + w2)), fmaxf(A.w + w3, B.x + w4));
    m.y = fmaxf(fmaxf(fmaxf(m.y, A.y + w0), fmaxf(A.z + w1, A.w + w2)), fmaxf(B.x + w3, B.y + w4));
    m.z = fmaxf(fmaxf(fmaxf(m.z, A.z + w0), fmaxf(A.w + w1, B.x + w2)), fmaxf(B.y + w3, B.z + w4));
    m.w = fmaxf(fmaxf(fmaxf(m.w, A.w + w0), fmaxf(B.x + w1, B.y + w2)), fmaxf(B.z + w3, B.w + w4));
    return m;
}

__device__ __forceinline__ void add4(float4& a, float4 m) {
    a.x += m.x; a.y += m.y; a.z += m.z; a.w += m.w;
}

__global__ __launch_bounds__(256, 4)
void closing_v3(const float* __restrict__ x, const float* __restrict__ wd,
                const float* __restrict__ we, float* __restrict__ out) {
    __shared__ __align__(16) float sx[CI * XCH];    // 21120 B
    __shared__ __align__(16) float sdil[36 * DS];   //  6336 B

    const int tid = threadIdx.x;
    const int bx = blockIdx.x, by = blockIdx.y, z = blockIdx.z;
    const int o = z & 15, b = z >> 4;
    const int i0 = by * TT, j0 = bx * TT;
    const float* xb = x + (size_t)b * (CI * HH * WW);

    // ---- stage all 3 channels (40x40 each, stride 44), edge clamp folded ----
#pragma unroll
    for (int k = 0; k < 19; ++k) {
        const int idx = tid + (k << 8);
        if (idx < CI * XR * XR) {
            const int c   = idx / 1600;
            const int rem = idx - c * 1600;
            const int rr  = rem / 40;
            const int cc  = rem - rr * 40;
            int gi = i0 - 4 + rr; gi = min(max(gi, 0), HH - 1);
            int gj = j0 - 4 + cc; gj = min(max(gj, 0), WW - 1);
            sx[c * XCH + rr * XS + cc] = xb[c * (HH * WW) + (gi << 8) + gj];
        }
    }
    __syncthreads();

    // ---- dilation: 81 tasks, each 4 rows x 4 cols of the 36x36 dilated tile ----
    if (tid < 81) {
        const int q = tid / 9, s = tid - q * 9;   // rows 4q..4q+3, cols 4s..4s+3
        float4 acc0 = {0,0,0,0}, acc1 = acc0, acc2 = acc0, acc3 = acc0;
#pragma unroll
        for (int c = 0; c < CI; ++c) {
            const float* wr = wd + (o * CI + c) * 25;     // uniform -> SGPRs
            const float* base = &sx[c * XCH + (4 * q) * XS + 4 * s];
            const float NEG = -FLT_MAX;
            float4 m0 = {NEG,NEG,NEG,NEG}, m1 = m0, m2 = m0, m3 = m0;
#pragma unroll
            for (int dd = 0; dd < 8; ++dd) {
                const float4 A = *(const float4*)(base + dd * XS);
                const float4 B = *(const float4*)(base + dd * XS + 4);
                // sx row 4q+dd feeds output row 4q+rr with weight row dd-rr
                if (dd <= 4)           m0 = dapp(m0, A, B, wr[dd*5+0], wr[dd*5+1], wr[dd*5+2], wr[dd*5+3], wr[dd*5+4]);
                if (dd >= 1 && dd <= 5){ const int k2 = dd-1;
                                       m1 = dapp(m1, A, B, wr[k2*5+0], wr[k2*5+1], wr[k2*5+2], wr[k2*5+3], wr[k2*5+4]); }
                if (dd >= 2 && dd <= 6){ const int k2 = dd-2;
                                       m2 = dapp(m2, A, B, wr[k2*5+0], wr[k2*5+1], wr[k2*5+2], wr[k2*5+3], wr[k2*5+4]); }
                if (dd >= 3)           { const int k2 = dd-3;
                                       m3 = dapp(m3, A, B, wr[k2*5+0], wr[k2*5+1], wr[k2*5+2], wr[k2*5+3], wr[k2*5+4]); }
            }
            add4(acc0, m0); add4(acc1, m1); add4(acc2, m2); add4(acc3, m3);
        }

        // column pad replication (erosion-input edge padding, fused)
        if (bx == 0 && s == 0) {   // local cols 0,1 phantom -> col 2
            acc0.x = acc0.y = acc0.z;  acc1.x = acc1.y = acc1.z;
            acc2.x = acc2.y = acc2.z;  acc3.x = acc3.y = acc3.z;
        }
        if (bx == 7 && s == 8) {   // local cols 34,35 phantom -> col 33
            acc0.z = acc0.w = acc0.y;  acc1.z = acc1.w = acc1.y;
            acc2.z = acc2.w = acc2.y;  acc3.z = acc3.w = acc3.y;
        }
        // row pad replication
        float4 w0 = acc0, w1 = acc1, w2 = acc2, w3 = acc3;
        if (by == 0 && q == 0) { w0 = acc2; w1 = acc2; }          // rows 0,1 <- row 2
        if (by == 7 && q == 8) { w2 = acc1; w3 = acc1; }          // rows 34,35 <- row 33
        float* dp = &sdil[(4 * q) * DS + 4 * s];
        *(float4*)(dp)          = w0;
        *(float4*)(dp + DS)     = w1;
        *(float4*)(dp + 2 * DS) = w2;
        *(float4*)(dp + 3 * DS) = w3;
    }
    __syncthreads();

    // ---- erosion: 128 tasks, each 1 row x 8 cols; branch-free ----
    if (tid < 128) {
        const int s = tid & 3, r = tid >> 2;      // row r, cols 8s..8s+7
        const float* ew = we + o * 25;            // uniform -> SGPRs
        const float* eb = &sdil[r * DS + 8 * s];
        const float PF = FLT_MAX;
        float4 r0 = {PF,PF,PF,PF}, r1 = r0;
#pragma unroll
        for (int dd = 0; dd < 5; ++dd) {
            const float4 A = *(const float4*)(eb + dd * DS);
            const float4 B = *(const float4*)(eb + dd * DS + 4);
            const float4 C = *(const float4*)(eb + dd * DS + 8);
            const float e0 = ew[dd*5+0], e1 = ew[dd*5+1], e2 = ew[dd*5+2],
                        e3 = ew[dd*5+3], e4 = ew[dd*5+4];
            r0.x = fminf(fminf(fminf(r0.x, A.x - e0), fminf(A.y - e1, A.z - e2)), fminf(A.w - e3, B.x - e4));
            r0.y = fminf(fminf(fminf(r0.y, A.y - e0), fminf(A.z - e1, A.w - e2)), fminf(B.x - e3, B.y - e4));
            r0.z = fminf(fminf(fminf(r0.z, A.z - e0), fminf(A.w - e1, B.x - e2)), fminf(B.y - e3, B.z - e4));
            r0.w = fminf(fminf(fminf(r0.w, A.w - e0), fminf(B.x - e1, B.y - e2)), fminf(B.z - e3, B.w - e4));
            r1.x = fminf(fminf(fminf(r1.x, B.x - e0), fminf(B.y - e1, B.z - e2)), fminf(B.w - e3, C.x - e4));
            r1.y = fminf(fminf(fminf(r1.y, B.y - e0), fminf(B.z - e1, B.w - e2)), fminf(C.x - e3, C.y - e4));
            r1.z = fminf(fminf(fminf(r1.z, B.z - e0), fminf(B.w - e1, C.x - e2)), fminf(C.y - e3, C.z - e4));
            r1.w = fminf(fminf(fminf(r1.w, B.w - e0), fminf(C.x - e1, C.y - e2)), fminf(C.z - e3, C.w - e4));
        }
        float* op = &out[((size_t)z << 16) + ((size_t)(i0 + r) << 8) + j0 + 8 * s];
        *(float4*)op       = r0;
        *(float4*)(op + 4) = r1;
    }
}

extern "C" void kernel_launch(void* const* d_in, const int* in_sizes, int n_in,
                              void* d_out, int out_size, void* d_ws, size_t ws_size,
                              hipStream_t stream) {
    const float* x  = (const float*)d_in[0];   // (4,3,256,256)
    const float* wd = (const float*)d_in[1];   // (16,3,5,5)
    const float* we = (const float*)d_in[2];   // (16,5,5)
    float* out = (float*)d_out;                // (4,16,256,256)

    dim3 grid(WW / TT, HH / TT, 4 * 16);       // (8, 8, 64)
    closing_v3<<<grid, dim3(256), 0, stream>>>(x, wd, we, out);
}

// Round 4
// 108.017 us; speedup vs baseline: 1.5811x; 1.0195x over previous
//
#include <hip/hip_runtime.h>
#include <float.h>

// Closing = erosion(identity) ∘ dilation(sum over CIN=3), K=5, edge padding.
// v4: output tile 56x64, 256 threads, grid (4, 5 row-bands (last overlaps), 64).
//  - dilation: 255 tasks of 4r x 4c (one pass, ~100% lanes, 1.0 b128/out/chan)
//  - erosion: 448 tasks of 1r x 8c (two passes), branch-free via pad replication
//    fused into dilation writeback
//  - sx stride 76 (19 granules, odd), sdil stride 68 (17, odd): uniform bank quads
//  - max3/min3-shaped trees; all state in named float4s (no spill; v2 lesson)
//  - LDS 74.7 KB -> 2 blocks/CU

namespace {
constexpr int HH = 256, WW = 256, CI = 3;
constexpr int TW = 64, TH = 56;   // output tile
constexpr int DS = 68;            // sdil row stride (floats)
constexpr int XS = 76;            // sx row stride (floats)
constexpr int XCH = 64 * XS;      // 4864 floats per channel (64 rows)
}

__device__ __forceinline__ float4 dapp(float4 m, float4 A, float4 B,
                                       float w0, float w1, float w2, float w3, float w4) {
    {   float u = fmaxf(fmaxf(A.x + w0, A.y + w1), A.z + w2);
        float v = fmaxf(fmaxf(u, A.w + w3), B.x + w4);
        m.x = fmaxf(m.x, v); }
    {   float u = fmaxf(fmaxf(A.y + w0, A.z + w1), A.w + w2);
        float v = fmaxf(fmaxf(u, B.x + w3), B.y + w4);
        m.y = fmaxf(m.y, v); }
    {   float u = fmaxf(fmaxf(A.z + w0, A.w + w1), B.x + w2);
        float v = fmaxf(fmaxf(u, B.y + w3), B.z + w4);
        m.z = fmaxf(m.z, v); }
    {   float u = fmaxf(fmaxf(A.w + w0, B.x + w1), B.y + w2);
        float v = fmaxf(fmaxf(u, B.z + w3), B.w + w4);
        m.w = fmaxf(m.w, v); }
    return m;
}

__device__ __forceinline__ void add4(float4& a, float4 m) {
    a.x += m.x; a.y += m.y; a.z += m.z; a.w += m.w;
}

__global__ __launch_bounds__(256, 2)
void closing_v4(const float* __restrict__ x, const float* __restrict__ wd,
                const float* __restrict__ we, float* __restrict__ out) {
    __shared__ __align__(16) float sx[CI * XCH];   // 58368 B
    __shared__ __align__(16) float sdil[60 * DS];  // 16320 B

    const int tid = threadIdx.x;
    const int bx = blockIdx.x, by = blockIdx.y, z = blockIdx.z;
    const int o = z & 15, b = z >> 4;
    const int i0 = min(by * TH, HH - TH);   // 0,56,112,168,200 (last band overlaps)
    const int j0 = bx * TW;
    const float* xb = x + (size_t)b * (CI * HH * WW);

    // ---- stage x: 3 channels x 64 rows x 72 cols (clamp folded) ----
    const bool colsafe = (bx != 0) && (bx != 3);   // cols j0-4..j0+67 in-bounds
    if (colsafe) {
#pragma unroll
        for (int k = 0; k < 14; ++k) {
            const int idx = tid + (k << 8);        // float4 index, 3456 total
            if (idx < 3456) {
                const int c   = idx / 1152;
                const int rem = idx - c * 1152;
                const int r   = rem / 18;
                const int cq  = rem - r * 18;
                int gi = i0 - 4 + r; gi = min(max(gi, 0), HH - 1);
                const float4 v = *(const float4*)&xb[c * (HH*WW) + (gi << 8) + (j0 - 4) + (cq << 2)];
                *(float4*)&sx[c * XCH + r * XS + (cq << 2)] = v;
            }
        }
    } else {
        for (int k = 0; k < 54; ++k) {             // 13824 = 54*256 exactly
            const int idx = tid + (k << 8);
            const int c   = idx / 4608;
            const int rem = idx - c * 4608;
            const int r   = rem / 72;
            const int col = rem - r * 72;
            int gi = i0 - 4 + r;   gi = min(max(gi, 0), HH - 1);
            int gj = j0 - 4 + col; gj = min(max(gj, 0), WW - 1);
            sx[c * XCH + r * XS + col] = xb[c * (HH*WW) + (gi << 8) + gj];
        }
    }
    __syncthreads();

    // ---- dilation: 255 tasks, each 4 rows x 4 cols of the 60x68 dilated tile ----
    if (tid < 255) {
        const int q = tid / 17, s = tid - q * 17;  // rows 4q..4q+3, cols 4s..4s+3
        float4 acc0 = {0,0,0,0}, acc1 = acc0, acc2 = acc0, acc3 = acc0;
#pragma unroll
        for (int c = 0; c < CI; ++c) {
            const float* wr = wd + (o * CI + c) * 25;   // uniform -> SGPRs
            const float* base = &sx[c * XCH + (4 * q) * XS + 4 * s];
            const float NEG = -FLT_MAX;
            float4 m0 = {NEG,NEG,NEG,NEG}, m1 = m0, m2 = m0, m3 = m0;
#pragma unroll
            for (int dd = 0; dd < 8; ++dd) {
                const float4 A = *(const float4*)(base + dd * XS);
                const float4 B = *(const float4*)(base + dd * XS + 4);
                if (dd <= 4)            m0 = dapp(m0, A, B, wr[dd*5+0], wr[dd*5+1], wr[dd*5+2], wr[dd*5+3], wr[dd*5+4]);
                if (dd >= 1 && dd <= 5) { const int k2 = dd-1;
                                        m1 = dapp(m1, A, B, wr[k2*5+0], wr[k2*5+1], wr[k2*5+2], wr[k2*5+3], wr[k2*5+4]); }
                if (dd >= 2 && dd <= 6) { const int k2 = dd-2;
                                        m2 = dapp(m2, A, B, wr[k2*5+0], wr[k2*5+1], wr[k2*5+2], wr[k2*5+3], wr[k2*5+4]); }
                if (dd >= 3)            { const int k2 = dd-3;
                                        m3 = dapp(m3, A, B, wr[k2*5+0], wr[k2*5+1], wr[k2*5+2], wr[k2*5+3], wr[k2*5+4]); }
            }
            add4(acc0, m0); add4(acc1, m1); add4(acc2, m2); add4(acc3, m3);
        }

        // column pad replication (erosion-input edge padding, fused)
        if (bx == 0 && s == 0) {      // local cols 0,1 phantom <- col 2
            acc0.x = acc0.y = acc0.z;  acc1.x = acc1.y = acc1.z;
            acc2.x = acc2.y = acc2.z;  acc3.x = acc3.y = acc3.z;
        }
        if (bx == 3 && s == 16) {     // local cols 66,67 phantom <- col 65
            acc0.z = acc0.w = acc0.y;  acc1.z = acc1.w = acc1.y;
            acc2.z = acc2.w = acc2.y;  acc3.z = acc3.w = acc3.y;
        }
        // row pad replication
        float4 w0 = acc0, w1 = acc1, w2 = acc2, w3 = acc3;
        if (i0 == 0        && q == 0)  { w0 = acc2; w1 = acc2; }  // rows 0,1 <- row 2
        if (i0 == HH - TH  && q == 14) { w2 = acc1; w3 = acc1; }  // rows 58,59 <- row 57
        float* dp = &sdil[(4 * q) * DS + 4 * s];
        *(float4*)(dp)          = w0;
        *(float4*)(dp + DS)     = w1;
        *(float4*)(dp + 2 * DS) = w2;
        *(float4*)(dp + 3 * DS) = w3;
    }
    __syncthreads();

    // ---- erosion: 448 tasks of 1 row x 8 cols; branch-free ----
    {
        const float* ew = we + o * 25;    // uniform -> SGPRs
        for (int t = tid; t < 448; t += 256) {
            const int r = t >> 3, s = t & 7;
            const float* eb = &sdil[r * DS + 8 * s];
            const float PF = FLT_MAX;
            float4 r0 = {PF,PF,PF,PF}, r1 = r0;
#pragma unroll
            for (int dd = 0; dd < 5; ++dd) {
                const float4 A = *(const float4*)(eb + dd * DS);
                const float4 B = *(const float4*)(eb + dd * DS + 4);
                const float4 C = *(const float4*)(eb + dd * DS + 8);
                const float e0 = ew[dd*5+0], e1 = ew[dd*5+1], e2 = ew[dd*5+2],
                            e3 = ew[dd*5+3], e4 = ew[dd*5+4];
                {   float u = fminf(fminf(A.x - e0, A.y - e1), A.z - e2);
                    float v = fminf(fminf(u, A.w - e3), B.x - e4);
                    r0.x = fminf(r0.x, v); }
                {   float u = fminf(fminf(A.y - e0, A.z - e1), A.w - e2);
                    float v = fminf(fminf(u, B.x - e3), B.y - e4);
                    r0.y = fminf(r0.y, v); }
                {   float u = fminf(fminf(A.z - e0, A.w - e1), B.x - e2);
                    float v = fminf(fminf(u, B.y - e3), B.z - e4);
                    r0.z = fminf(r0.z, v); }
                {   float u = fminf(fminf(A.w - e0, B.x - e1), B.y - e2);
                    float v = fminf(fminf(u, B.z - e3), B.w - e4);
                    r0.w = fminf(r0.w, v); }
                {   float u = fminf(fminf(B.x - e0, B.y - e1), B.z - e2);
                    float v = fminf(fminf(u, B.w - e3), C.x - e4);
                    r1.x = fminf(r1.x, v); }
                {   float u = fminf(fminf(B.y - e0, B.z - e1), B.w - e2);
                    float v = fminf(fminf(u, C.x - e3), C.y - e4);
                    r1.y = fminf(r1.y, v); }
                {   float u = fminf(fminf(B.z - e0, B.w - e1), C.x - e2);
                    float v = fminf(fminf(u, C.y - e3), C.z - e4);
                    r1.z = fminf(r1.z, v); }
                {   float u = fminf(fminf(B.w - e0, C.x - e1), C.y - e2);
                    float v = fminf(fminf(u, C.z - e3), C.w - e4);
                    r1.w = fminf(r1.w, v); }
            }
            float* op = &out[((size_t)z << 16) + ((size_t)(i0 + r) << 8) + j0 + 8 * s];
            *(float4*)op       = r0;
            *(float4*)(op + 4) = r1;
        }
    }
}

extern "C" void kernel_launch(void* const* d_in, const int* in_sizes, int n_in,
                              void* d_out, int out_size, void* d_ws, size_t ws_size,
                              hipStream_t stream) {
    const float* x  = (const float*)d_in[0];   // (4,3,256,256)
    const float* wd = (const float*)d_in[1];   // (16,3,5,5)
    const float* we = (const float*)d_in[2];   // (16,5,5)
    float* out = (float*)d_out;                // (4,16,256,256)

    dim3 grid(WW / TW, 5, 4 * 16);             // (4, 5, 64); band 4 overlaps band 3
    closing_v4<<<grid, dim3(256), 0, stream>>>(x, wd, we, out);
}

// Round 5
// 97.570 us; speedup vs baseline: 1.7504x; 1.1071x over previous
//
#include <hip/hip_runtime.h>
#include <float.h>

// Closing = erosion(identity) ∘ dilation(sum over CIN=3), K=5, edge padding.
// v5 = v1 shape (32x32 tile, all threads busy, 5 blocks/CU) + v3 odd strides
//      + v4 direct-float4 trees + in-task pad replication (branch-free erosion).
//  - dilation: 108 tasks of 3r x 4c (7 window rows x 2 b128/chan = 1.17/out/chan)
//  - erosion: 256 tasks of 1r x 4c, bank map (11r+s)%8 uniform
//  - LDS: sx 3x40 rows @ stride 44 (21.1KB) + sdil 36 @ stride 44 (6.3KB)
//  - all state in named float4s (no arrays -> no scratch spill; v2 lesson)

namespace {
constexpr int HH = 256, WW = 256, CI = 3;
constexpr int TT = 32;            // output tile
constexpr int XS = 44;            // sx row stride (floats), odd quad count
constexpr int XCH = 40 * XS;      // 1760 floats per channel
constexpr int DS = 44;            // sdil row stride
}

__device__ __forceinline__ float4 dapp(float4 m, float4 A, float4 B, const float* w5) {
    const float w0 = w5[0], w1 = w5[1], w2 = w5[2], w3 = w5[3], w4 = w5[4];
    {   float u = fmaxf(fmaxf(A.x + w0, A.y + w1), A.z + w2);
        m.x = fmaxf(m.x, fmaxf(fmaxf(u, A.w + w3), B.x + w4)); }
    {   float u = fmaxf(fmaxf(A.y + w0, A.z + w1), A.w + w2);
        m.y = fmaxf(m.y, fmaxf(fmaxf(u, B.x + w3), B.y + w4)); }
    {   float u = fmaxf(fmaxf(A.z + w0, A.w + w1), B.x + w2);
        m.z = fmaxf(m.z, fmaxf(fmaxf(u, B.y + w3), B.z + w4)); }
    {   float u = fmaxf(fmaxf(A.w + w0, B.x + w1), B.y + w2);
        m.w = fmaxf(m.w, fmaxf(fmaxf(u, B.z + w3), B.w + w4)); }
    return m;
}

__device__ __forceinline__ void add4(float4& a, float4 m) {
    a.x += m.x; a.y += m.y; a.z += m.z; a.w += m.w;
}

__global__ __launch_bounds__(256, 5)
void closing_v5(const float* __restrict__ x, const float* __restrict__ wd,
                const float* __restrict__ we, float* __restrict__ out) {
    __shared__ __align__(16) float sx[CI * XCH];    // 21120 B
    __shared__ __align__(16) float sdil[36 * DS];   //  6336 B

    const int tid = threadIdx.x;
    const int bx = blockIdx.x, by = blockIdx.y, z = blockIdx.z;
    const int o = z & 15, b = z >> 4;
    const int i0 = by * TT, j0 = bx * TT;
    const float* xb = x + (size_t)b * (CI * HH * WW);

    // ---- stage all 3 channels: 40x40 each at stride 44, clamp folded ----
#pragma unroll
    for (int k = 0; k < 19; ++k) {
        const int idx = tid + (k << 8);
        if (idx < CI * 1600) {
            const int c   = idx / 1600;
            const int rem = idx - c * 1600;
            const int rr  = rem / 40;
            const int cc  = rem - rr * 40;
            int gi = i0 - 4 + rr; gi = min(max(gi, 0), HH - 1);
            int gj = j0 - 4 + cc; gj = min(max(gj, 0), WW - 1);
            sx[c * XCH + rr * XS + cc] = xb[c * (HH * WW) + (gi << 8) + gj];
        }
    }
    __syncthreads();

    // ---- dilation: 108 tasks of 3 rows x 4 cols over the 36x36 dilated tile ----
    if (tid < 108) {
        const int q = tid / 9, s = tid - q * 9;   // rows 3q..3q+2, cols 4s..4s+3
        float4 acc0 = {0,0,0,0}, acc1 = acc0, acc2 = acc0;
#pragma unroll
        for (int c = 0; c < CI; ++c) {
            const float* wr = wd + (o * CI + c) * 25;      // uniform -> SGPRs
            const float* base = &sx[c * XCH + (3 * q) * XS + 4 * s];
            const float NEG = -FLT_MAX;
            float4 m0 = {NEG,NEG,NEG,NEG}, m1 = m0, m2 = m0;
#pragma unroll
            for (int dr = 0; dr < 7; ++dr) {
                const float4 A = *(const float4*)(base + dr * XS);
                const float4 B = *(const float4*)(base + dr * XS + 4);
                if (dr <= 4)            m0 = dapp(m0, A, B, wr + dr * 5);
                if (dr >= 1 && dr <= 5) m1 = dapp(m1, A, B, wr + (dr - 1) * 5);
                if (dr >= 2)            m2 = dapp(m2, A, B, wr + (dr - 2) * 5);
            }
            add4(acc0, m0); add4(acc1, m1); add4(acc2, m2);
        }

        // column pad replication (erosion-input edge padding, fused, in-task)
        if (bx == 0 && s == 0) {      // local cols 0,1 phantom <- col 2
            acc0.x = acc0.y = acc0.z;  acc1.x = acc1.y = acc1.z;  acc2.x = acc2.y = acc2.z;
        }
        if (bx == 7 && s == 8) {      // local cols 34,35 phantom <- col 33
            acc0.z = acc0.w = acc0.y;  acc1.z = acc1.w = acc1.y;  acc2.z = acc2.w = acc2.y;
        }
        // row pad replication (rows 0,1 <- row 2 live in task q=0; 34,35 <- 33 in q=11)
        float4 w0 = acc0, w1 = acc1, w2 = acc2;
        if (by == 0 && q == 0)  { w0 = acc2; w1 = acc2; }
        if (by == 7 && q == 11) { w1 = acc0; w2 = acc0; }
        float* dp = &sdil[(3 * q) * DS + 4 * s];
        *(float4*)(dp)          = w0;
        *(float4*)(dp + DS)     = w1;
        *(float4*)(dp + 2 * DS) = w2;
    }
    __syncthreads();

    // ---- erosion: 256 tasks of 1 row x 4 cols; branch-free ----
    {
        const int r = tid >> 3, s = tid & 7;      // out row r, cols 4s..4s+3
        const float* ew = we + o * 25;            // uniform -> SGPRs
        const float* eb = &sdil[r * DS + 4 * s];
        const float PF = FLT_MAX;
        float4 r0 = {PF, PF, PF, PF};
#pragma unroll
        for (int dd = 0; dd < 5; ++dd) {
            const float4 A = *(const float4*)(eb + dd * DS);
            const float4 B = *(const float4*)(eb + dd * DS + 4);
            const float e0 = ew[dd*5+0], e1 = ew[dd*5+1], e2 = ew[dd*5+2],
                        e3 = ew[dd*5+3], e4 = ew[dd*5+4];
            {   float u = fminf(fminf(A.x - e0, A.y - e1), A.z - e2);
                r0.x = fminf(r0.x, fminf(fminf(u, A.w - e3), B.x - e4)); }
            {   float u = fminf(fminf(A.y - e0, A.z - e1), A.w - e2);
                r0.y = fminf(r0.y, fminf(fminf(u, B.x - e3), B.y - e4)); }
            {   float u = fminf(fminf(A.z - e0, A.w - e1), B.x - e2);
                r0.z = fminf(r0.z, fminf(fminf(u, B.y - e3), B.z - e4)); }
            {   float u = fminf(fminf(A.w - e0, B.x - e1), B.y - e2);
                r0.w = fminf(r0.w, fminf(fminf(u, B.z - e3), B.w - e4)); }
        }
        *(float4*)&out[((size_t)z << 16) + ((size_t)(i0 + r) << 8) + j0 + 4 * s] = r0;
    }
}

extern "C" void kernel_launch(void* const* d_in, const int* in_sizes, int n_in,
                              void* d_out, int out_size, void* d_ws, size_t ws_size,
                              hipStream_t stream) {
    const float* x  = (const float*)d_in[0];   // (4,3,256,256)
    const float* wd = (const float*)d_in[1];   // (16,3,5,5)
    const float* we = (const float*)d_in[2];   // (16,5,5)
    float* out = (float*)d_out;                // (4,16,256,256)

    dim3 grid(WW / TT, HH / TT, 4 * 16);       // (8, 8, 64)
    closing_v5<<<grid, dim3(256), 0, stream>>>(x, wd, we, out);
}